// Round 6
// baseline (216.036 us; speedup 1.0000x reference)
//
#include <hip/hip_runtime.h>
#include <math.h>

#define S_LEN 2048
#define B_SZ 2
#define NH 8
#define DH 64
#define DM 512
#define MROWS 4096  // B*S

typedef __attribute__((ext_vector_type(8))) short s16x8;
typedef __attribute__((ext_vector_type(4))) float fx4;
typedef __attribute__((ext_vector_type(16))) float fx16;
typedef __attribute__((ext_vector_type(4))) int ix4;

__device__ inline short f2bf(float x){
  unsigned u = __float_as_uint(x);
  u = (u + 0x7FFFu + ((u >> 16) & 1u)) >> 16;
  return (short)u;
}

__device__ inline fx4 mfma16(s16x8 a, s16x8 b, fx4 c){
  return __builtin_amdgcn_mfma_f32_16x16x32_bf16(a, b, c, 0, 0, 0);
}
__device__ inline fx16 mfma32(s16x8 a, s16x8 b, fx16 c){
  return __builtin_amdgcn_mfma_f32_32x32x16_bf16(a, b, c, 0, 0, 0);
}
__device__ inline int cvtpk(float a, float b){
  int r; asm("v_cvt_pk_bf16_f32 %0, %1, %2" : "=v"(r) : "v"(a), "v"(b)); return r;
}

#define GLL16(g, l) __builtin_amdgcn_global_load_lds((const __attribute__((address_space(1))) void*)(g), (__attribute__((address_space(3))) void*)(l), 16, 0, 0)
#define GLL4(g, l)  __builtin_amdgcn_global_load_lds((const __attribute__((address_space(1))) void*)(g), (__attribute__((address_space(3))) void*)(l), 4, 0, 0)

// ---- K0: fused weight-transpose (blocks 0..255) + logmap (blocks 256..2303) ----
__global__ __launch_bounds__(256) void prep_kernel(const float* __restrict__ W0,
                                                   const float* __restrict__ W1,
                                                   const float* __restrict__ W2,
                                                   const float* __restrict__ W3,
                                                   short* __restrict__ Wt,
                                                   const float* __restrict__ x,
                                                   short* __restrict__ xeu){
  __shared__ short tile[64][66];
  __shared__ float s4[4];
  int bid = blockIdx.x;
  int t = threadIdx.x;
  if (bid < 256){
    int z = bid >> 6, rem = bid & 63;
    const float* W = (z == 0) ? W0 : (z == 1) ? W1 : (z == 2) ? W2 : W3;
    short* Wtz = Wt + (size_t)z * DM * DM;
    int n0 = (rem & 7) * 64, k0 = (rem >> 3) * 64;
    int nl = t & 63;
    #pragma unroll
    for (int p = 0; p < 16; ++p){
      int kl = (t >> 6) + p * 4;
      tile[kl][nl] = f2bf(W[(size_t)(k0 + kl) * DM + n0 + nl]);
    }
    __syncthreads();
    int kl2 = t & 63;
    #pragma unroll
    for (int p = 0; p < 16; ++p){
      int nl2 = (t >> 6) + p * 4;
      Wtz[(size_t)(n0 + nl2) * DM + k0 + kl2] = tile[kl2][nl2];
    }
  } else {
    int row = 2 * (bid - 256) + (t >> 7);
    int tl = t & 127;
    const float* xr = x + (size_t)row * (DM + 1);
    float v[4]; float ss = 0.f;
    #pragma unroll
    for (int j = 0; j < 4; ++j){
      v[j] = xr[1 + tl + 128 * j];
      ss += v[j] * v[j];
    }
    #pragma unroll
    for (int off = 1; off < 64; off <<= 1) ss += __shfl_xor(ss, off);
    if ((t & 63) == 0) s4[t >> 6] = ss;
    __syncthreads();
    int g2 = t >> 7;
    float tot = s4[2 * g2] + s4[2 * g2 + 1];
    float nrm = sqrtf(tot);
    float xt = xr[0];
    float theta = acoshf(fmaxf(xt, 1.0f + 1e-7f));
    float scl = theta / fmaxf(nrm, 1e-7f);
    #pragma unroll
    for (int j = 0; j < 4; ++j)
      xeu[(size_t)row * DM + tl + 128 * j] = f2bf(scl * v[j]);
  }
}

// ---- K2: QKV GEMM + fused exp-map / V-transpose. Single-barrier pipelined loop.
// grid (32 m-tiles, 8 heads, 3 z): same-A blocks spaced 32 -> same XCD.
__global__ __launch_bounds__(256, 3) void gemm_fused_kernel(const short* __restrict__ A,
                                                            const short* __restrict__ Bt,
                                                            const float* __restrict__ labsK,
                                                            float* __restrict__ Qt,
                                                            short* __restrict__ Qs,
                                                            float* __restrict__ Kt,
                                                            short* __restrict__ Ks,
                                                            short* __restrict__ Vt){
  __shared__ __attribute__((aligned(16))) short Asm[2][128 * 64];
  __shared__ __attribute__((aligned(16))) short Bsm[2][64 * 64];
  __shared__ float nrm2s[2][128];
  const int K = DM;
  int z = blockIdx.z;
  int h = blockIdx.y;                 // head
  int n0 = h * 64, m0 = blockIdx.x * 128;
  int t = threadIdx.x;
  int w = t >> 6, lane = t & 63;
  int wm = w >> 1, wn = w & 1;
  int lg = lane >> 4, lr = lane & 15;
  const short* Btz = Bt + (size_t)z * K * DM;

  int aoff[4]; const short* asrcp[4];
  int boff[2]; const short* bsrcp[2];
  #pragma unroll
  for (int j = 0; j < 4; ++j){
    int ch = t + 256 * j;
    int r = ch >> 3, c = ch & 7;
    aoff[j] = ch * 8;
    asrcp[j] = A + (size_t)(m0 + r) * K + 8 * (c ^ (r & 7));
  }
  #pragma unroll
  for (int j = 0; j < 2; ++j){
    int ch = t + 256 * j;
    int r = ch >> 3, c = ch & 7;
    boff[j] = ch * 8;
    bsrcp[j] = Btz + (size_t)(n0 + r) * K + 8 * (c ^ (r & 7));
  }

  // prologue: stage k-step 0 into buf 0
  {
    short* ab = &Asm[0][0]; short* bb = &Bsm[0][0];
    #pragma unroll
    for (int j = 0; j < 4; ++j) GLL16(asrcp[j], ab + aoff[j]);
    #pragma unroll
    for (int j = 0; j < 2; ++j) GLL16(bsrcp[j], bb + boff[j]);
  }

  fx4 acc[4][2] = {};
  for (int ks = 0; ks < 8; ++ks){
    asm volatile("s_waitcnt vmcnt(0)" ::: "memory");
    __builtin_amdgcn_s_barrier();
    if (ks < 7){
      int nb = (ks + 1) & 1;
      short* ab = &Asm[nb][0]; short* bb = &Bsm[nb][0];
      int kk = (ks + 1) * 64;
      #pragma unroll
      for (int j = 0; j < 4; ++j) GLL16(asrcp[j] + kk, ab + aoff[j]);
      #pragma unroll
      for (int j = 0; j < 2; ++j) GLL16(bsrcp[j] + kk, bb + boff[j]);
    }
    int buf = ks & 1;
    s16x8 af[4][2], bf[2][2];
    #pragma unroll
    for (int mi = 0; mi < 4; ++mi){
      int row = wm * 64 + mi * 16 + lr;
      #pragma unroll
      for (int s = 0; s < 2; ++s)
        af[mi][s] = *(const s16x8*)&Asm[buf][row * 64 + ((4 * s + lg) ^ (row & 7)) * 8];
    }
    #pragma unroll
    for (int ni = 0; ni < 2; ++ni){
      int row = wn * 32 + ni * 16 + lr;
      #pragma unroll
      for (int s = 0; s < 2; ++s)
        bf[ni][s] = *(const s16x8*)&Bsm[buf][row * 64 + ((4 * s + lg) ^ (row & 7)) * 8];
    }
    __builtin_amdgcn_s_setprio(1);
    #pragma unroll
    for (int s = 0; s < 2; ++s)
      #pragma unroll
      for (int mi = 0; mi < 4; ++mi)
        #pragma unroll
        for (int ni = 0; ni < 2; ++ni)
          acc[mi][ni] = mfma16(af[mi][s], bf[ni][s], acc[mi][ni]);
    __builtin_amdgcn_s_setprio(0);
  }

  if (z < 2){
    // ---- fused exp-map epilogue (Q or K) ----
    #pragma unroll
    for (int mi = 0; mi < 4; ++mi)
      #pragma unroll
      for (int r = 0; r < 4; ++r){
        float prt = acc[mi][0][r] * acc[mi][0][r] + acc[mi][1][r] * acc[mi][1][r];
        prt += __shfl_xor(prt, 1);
        prt += __shfl_xor(prt, 2);
        prt += __shfl_xor(prt, 4);
        prt += __shfl_xor(prt, 8);
        if (lr == 0) nrm2s[wn][wm * 64 + mi * 16 + 4 * lg + r] = prt;
      }
    __syncthreads();
    float c  = __expf(labsK[h]);
    float sc = sqrtf(c);
    float invsc = __frcp_rn(sc);
    float a  = 0.125f * c * 1.4426950408889634f;
    float tmul = (z == 0) ? a : 1.0f;
    float vmul = (z == 0) ? -a : 1.0f;
    float* Tt = (z == 0) ? Qt : Kt;
    short* Ts = (z == 0) ? Qs : Ks;
    #pragma unroll
    for (int mi = 0; mi < 4; ++mi)
      #pragma unroll
      for (int r = 0; r < 4; ++r){
        int row_local = wm * 64 + mi * 16 + 4 * lg + r;
        float full = nrm2s[0][row_local] + nrm2s[1][row_local];
        float n = fmaxf(sqrtf(full), 1e-7f);
        float arg = sc * n;
        float e = __expf(arg), ei = __frcp_rn(e);
        float tval = tmul * 0.5f * (e + ei) * invsc;
        float vscl = vmul * 0.5f * (e - ei) * __frcp_rn(arg);
        int grow = m0 + row_local;
        int b = grow >> 11, s = grow & (S_LEN - 1);
        size_t bhs = ((size_t)(b * NH + h) * S_LEN + s);
        if (lr == 0) Tt[bhs] = tval;
        #pragma unroll
        for (int ni = 0; ni < 2; ++ni)
          Ts[bhs * DH + wn * 32 + ni * 16 + lr] = f2bf(vscl * acc[mi][ni][r]);
      }
  } else {
    // ---- fused V transpose: acc -> LDS [64 d][136 pad] -> Vt (bh,d,s) bf16 ----
    short* vt = (short*)&Asm[0][0];
    __syncthreads();
    #pragma unroll
    for (int mi = 0; mi < 4; ++mi)
      #pragma unroll
      for (int ni = 0; ni < 2; ++ni)
        #pragma unroll
        for (int r = 0; r < 4; ++r){
          int row_local = wm * 64 + mi * 16 + 4 * lg + r;
          int col_local = wn * 32 + ni * 16 + lr;
          vt[col_local * 136 + row_local] = f2bf(acc[mi][ni][r]);
        }
    __syncthreads();
    int d = t >> 2, sseg = (t & 3) * 32;
    int b = m0 >> 11;
    size_t vbase = ((size_t)(b * NH + h) * DH + d) * S_LEN + (m0 & (S_LEN - 1)) + sseg;
    #pragma unroll
    for (int j = 0; j < 4; ++j){
      s16x8 val = *(const s16x8*)&vt[d * 136 + sseg + 8 * j];
      *(s16x8*)(Vt + vbase + 8 * j) = val;
    }
  }
}

// ---- K4: flash attention, key-split chunks, 3-buffer ring + counted vmcnt,
//      single barrier/tile, fused split-K finisher-combine (atomic counter). ----
__global__ __launch_bounds__(256, 3) void attn_kernel(const short* __restrict__ Qs,
                                                      const float* __restrict__ Qt,
                                                      const short* __restrict__ Ks,
                                                      const float* __restrict__ Kt,
                                                      const short* __restrict__ Vt,
                                                      float* __restrict__ Mpart,
                                                      float* __restrict__ Lpart,
                                                      float* __restrict__ Opart,
                                                      int* __restrict__ cnt,
                                                      short* __restrict__ Obf){
  __shared__ __attribute__((aligned(16))) short Ksm[3][4096];
  __shared__ __attribute__((aligned(16))) short Vsm[3][4096];
  __shared__ __attribute__((aligned(16))) float Ktm[3][64];
  __shared__ int lastFlag;

  int bx = blockIdx.x;
  int bh = bx & 15;                 // XCD-local heads
  int id = bx >> 4;                 // 0..39
  int g, c;
  if (id < 4)       { g = id;                 c = 0; }
  else if (id < 12) { g = 4 + ((id - 4) >> 1);  c = (id - 4) & 1; }
  else if (id < 24) { int r = id - 12; int q3 = r / 3; g = 8 + q3; c = r - 3 * q3; }
  else              { g = 12 + ((id - 24) >> 2); c = (id - 24) & 3; }
  int nch = (g >> 2) + 1;
  int kbeg = 512 * c;
  int kend = 512 * c + 512; { int ge = 128 * g + 128; if (ge < kend) kend = ge; }
  int ntc = (kend - kbeg) >> 6;

  int tid = threadIdx.x;
  int w = tid >> 6, lane = tid & 63;
  int l5 = lane & 31, hi = lane >> 5;
  size_t bhS = (size_t)bh * S_LEN;

  const short* Kg  = Ks + bhS * DH;
  const short* Vg  = Vt + (size_t)bh * DH * S_LEN;
  const float* Ktg = Kt + bhS;

  int srow = lane >> 3;
  int scol = ((lane & 7) * 8) ^ (srow << 3);
  const short* kg0 = Kg + (size_t)(kbeg + 16 * w + srow) * DH + scol;
  const short* kg1 = kg0 + 8 * DH;
  const short* vg0 = Vg + (size_t)(16 * w + srow) * S_LEN + kbeg + scol;
  const short* vg1 = vg0 + 8 * S_LEN;
  const float* ktg = Ktg + kbeg + lane;

  int q0w = 128 * g + 32 * w;
  int q   = q0w + l5;
  int qmax = q0w + 31;
  s16x8 qf[4];
  #pragma unroll
  for (int dblk = 0; dblk < 4; ++dblk)
    qf[dblk] = *(const s16x8*)(Qs + (bhS + q) * DH + dblk * 16 + hi * 8);
  float aqt = Qt[bhS + q];

  fx16 acc0, acc1;
  #pragma unroll
  for (int i = 0; i < 16; ++i){ acc0[i] = 0.f; acc1[i] = 0.f; }
  float mrun = 0.f, lrun = 0.f;

  #define STAGE_T(tt, b) { int off_ = (tt) * 64; \
    GLL16(kg0 + (size_t)off_ * DH, &Ksm[b][16 * w * 64]); \
    GLL16(kg1 + (size_t)off_ * DH, &Ksm[b][16 * w * 64 + 512]); \
    GLL16(vg0 + off_, &Vsm[b][16 * w * 64]); \
    GLL16(vg1 + off_, &Vsm[b][16 * w * 64 + 512]); \
    if (w == 3) GLL4(ktg + off_, &Ktm[b][0]); }

  STAGE_T(0, 0);
  if (ntc > 1) STAGE_T(1, 1);

  int buf = 0, sbuf = 2;
  for (int t = 0; t < ntc; ++t){
    int k0 = kbeg + t * 64;
    if (t + 1 < ntc){
      if (w == 3) asm volatile("s_waitcnt vmcnt(5)" ::: "memory");
      else        asm volatile("s_waitcnt vmcnt(4)" ::: "memory");
    } else {
      asm volatile("s_waitcnt vmcnt(0)" ::: "memory");
    }
    __builtin_amdgcn_s_barrier();
    if (t + 2 < ntc) STAGE_T(t + 2, sbuf);

    if (k0 <= qmax){
      fx16 st[2];
      __builtin_amdgcn_s_setprio(1);
      #pragma unroll
      for (int s = 0; s < 2; ++s){
        const short* kb = &Ksm[buf][(32 * s + l5) * 64];
        fx16 z;
        #pragma unroll
        for (int i = 0; i < 16; ++i) z[i] = 0.f;
        #pragma unroll
        for (int dblk = 0; dblk < 4; ++dblk){
          s16x8 kf = *(const s16x8*)(kb + ((16 * dblk + 8 * hi) ^ ((l5 & 7) << 3)));
          z = mfma32(kf, qf[dblk], z);
        }
        st[s] = z;
      }
      __builtin_amdgcn_s_setprio(0);
      float p[2][16];
      #pragma unroll
      for (int s = 0; s < 2; ++s)
        #pragma unroll
        for (int m4 = 0; m4 < 4; ++m4){
          fx4 kt4 = *(const fx4*)&Ktm[buf][32 * s + 8 * m4 + 4 * hi];
          #pragma unroll
          for (int tt = 0; tt < 4; ++tt)
            p[s][4 * m4 + tt] = st[s][4 * m4 + tt] + aqt * kt4[tt];
        }
      if (k0 + 63 > q0w){
        #pragma unroll
        for (int s = 0; s < 2; ++s)
          #pragma unroll
          for (int r = 0; r < 16; ++r){
            int kg2 = k0 + 32 * s + (r & 3) + 8 * (r >> 2) + 4 * hi;
            if (kg2 > q) p[s][r] = -3e38f;
          }
      }
      float v16[16];
      #pragma unroll
      for (int i = 0; i < 16; ++i) v16[i] = fmaxf(p[0][i], p[1][i]);
      #pragma unroll
      for (int i = 0; i < 8; ++i) v16[i] = fmaxf(v16[i], v16[i + 8]);
      #pragma unroll
      for (int i = 0; i < 4; ++i) v16[i] = fmaxf(v16[i], v16[i + 4]);
      float pmax = fmaxf(fmaxf(v16[0], v16[1]), fmaxf(v16[2], v16[3]));
      pmax = fmaxf(pmax, __shfl_xor(pmax, 32));
      if (!__all(pmax <= mrun + 8.f)){
        float mnew = fmaxf(mrun, pmax);
        float scl = __builtin_amdgcn_exp2f(mrun - mnew);
        mrun = mnew;
        lrun *= scl;
        #pragma unroll
        for (int i = 0; i < 16; ++i){ acc0[i] *= scl; acc1[i] *= scl; }
      }
      float sm[16];
      #pragma unroll
      for (int i = 0; i < 16; ++i){
        p[0][i] = __builtin_amdgcn_exp2f(p[0][i] - mrun);
        p[1][i] = __builtin_amdgcn_exp2f(p[1][i] - mrun);
        sm[i] = p[0][i] + p[1][i];
      }
      #pragma unroll
      for (int i = 0; i < 8; ++i) sm[i] += sm[i + 8];
      #pragma unroll
      for (int i = 0; i < 4; ++i) sm[i] += sm[i + 4];
      float rsum = (sm[0] + sm[1]) + (sm[2] + sm[3]);
      rsum += __shfl_xor(rsum, 32);
      lrun += rsum;

      #pragma unroll
      for (int h = 0; h < 4; ++h){
        int s = h >> 1, hb = h & 1;
        int w0 = cvtpk(p[s][8 * hb + 0], p[s][8 * hb + 1]);
        int w1 = cvtpk(p[s][8 * hb + 2], p[s][8 * hb + 3]);
        int w2 = cvtpk(p[s][8 * hb + 4], p[s][8 * hb + 5]);
        int w3 = cvtpk(p[s][8 * hb + 6], p[s][8 * hb + 7]);
        int sdA = hi ? w0 : w2;
        int sdB = hi ? w1 : w3;
        int rcA = __shfl_xor(sdA, 32);
        int rcB = __shfl_xor(sdB, 32);
        ix4 fw;
        fw.x = hi ? rcA : w0; fw.y = hi ? rcB : w1;
        fw.z = hi ? w2 : rcA; fw.w = hi ? w3 : rcB;
        s16x8 pf = __builtin_bit_cast(s16x8, fw);
        const short* vb0 = &Vsm[buf][(l5) * 64 + ((16 * h + 8 * hi) ^ ((l5 & 7) << 3))];
        const short* vb1 = vb0 + 32 * 64;
        s16x8 vf0 = *(const s16x8*)vb0;
        s16x8 vf1 = *(const s16x8*)vb1;
        __builtin_amdgcn_s_setprio(1);
        acc0 = mfma32(vf0, pf, acc0);
        acc1 = mfma32(vf1, pf, acc1);
        __builtin_amdgcn_s_setprio(0);
      }
    }
    buf  = (buf == 2)  ? 0 : buf + 1;
    sbuf = (sbuf == 2) ? 0 : sbuf + 1;
  }

  // ---- store partials: [q within 128][64 d] f32, plus m/l per q ----
  int slot = ((bh << 4) + g) * 4 + c;
  int qi = 32 * w + l5;
  if (hi == 0){
    Mpart[(size_t)slot * 128 + qi] = mrun;
    Lpart[(size_t)slot * 128 + qi] = lrun;
  }
  float* Op = Opart + (size_t)slot * 8192 + (size_t)qi * 64;
  #pragma unroll
  for (int j = 0; j < 4; ++j){
    fx4 v0, v1;
    #pragma unroll
    for (int i = 0; i < 4; ++i){ v0[i] = acc0[4 * j + i]; v1[i] = acc1[4 * j + i]; }
    *(fx4*)(Op + 8 * j + 4 * hi)      = v0;
    *(fx4*)(Op + 32 + 8 * j + 4 * hi) = v1;
  }

  // ---- split-K finisher: last block of (bh,g) combines and writes Obf ----
  __threadfence();
  if (tid == 0){
    int old = __hip_atomic_fetch_add(&cnt[(bh << 4) + g], 1,
                                     __ATOMIC_ACQ_REL, __HIP_MEMORY_SCOPE_AGENT);
    lastFlag = (old == nch - 1);
  }
  __syncthreads();
  if (lastFlag){
    __threadfence();
    int qf2 = tid & 127;            // q within group
    int oct0 = tid >> 7;            // 0..1
    int gbase = ((bh << 4) + g) * 4;
    float mc[4], lc[4];
    #pragma unroll
    for (int cc = 0; cc < 4; ++cc){
      mc[cc] = Mpart[(size_t)(gbase + cc) * 128 + qf2];
      lc[cc] = Lpart[(size_t)(gbase + cc) * 128 + qf2];
      if (cc >= nch) mc[cc] = -3e38f;
    }
    float M = fmaxf(fmaxf(mc[0], mc[1]), fmaxf(mc[2], mc[3]));
    float wc[4]; float L = 0.f;
    #pragma unroll
    for (int cc = 0; cc < 4; ++cc){
      wc[cc] = __builtin_amdgcn_exp2f(mc[cc] - M);
      L += wc[cc] * lc[cc];
    }
    float invL = 1.f / L;
    #pragma unroll
    for (int cc = 0; cc < 4; ++cc) wc[cc] *= invL;
    int bb = bh >> 3, hh = bh & 7;
    short* orow = Obf + ((size_t)bb * S_LEN + 128 * g + qf2) * DM + hh * DH;
    const float* obase = Opart + (size_t)gbase * 8192 + (size_t)qf2 * 64;
    #pragma unroll
    for (int i = 0; i < 4; ++i){
      int oct = oct0 + 2 * i;
      float accf[8] = {0.f,0.f,0.f,0.f,0.f,0.f,0.f,0.f};
      #pragma unroll
      for (int cc = 0; cc < 4; ++cc){
        fx4 a = *(const fx4*)(obase + (size_t)cc * 8192 + oct * 8);
        fx4 b = *(const fx4*)(obase + (size_t)cc * 8192 + oct * 8 + 4);
        #pragma unroll
        for (int k = 0; k < 4; ++k){ accf[k] += wc[cc] * a[k]; accf[4 + k] += wc[cc] * b[k]; }
      }
      s16x8 pk;
      #pragma unroll
      for (int dd = 0; dd < 8; ++dd) pk[dd] = f2bf(accf[dd]);
      *(s16x8*)(orow + oct * 8) = pk;
    }
  }
}

// ---- K5: O-projection GEMM, 64x64 tiles, single-barrier loop.
// grid (64 m, 8 n): same-A blocks spaced 64 -> same XCD.
__global__ __launch_bounds__(256, 4) void gemm_o_kernel(const short* __restrict__ A,
                                                        const short* __restrict__ Bt,
                                                        float* __restrict__ C){
  __shared__ __attribute__((aligned(16))) short Asm[2][64 * 64];
  __shared__ __attribute__((aligned(16))) short Bsm[2][64 * 64];
  const int K = DM;
  int n0 = blockIdx.y * 64, m0 = blockIdx.x * 64;
  int t = threadIdx.x;
  int w = t >> 6, lane = t & 63;
  int wm = w >> 1, wn = w & 1;
  int lg = lane >> 4, lr = lane & 15;

  int aoff[2]; const short* asrcp[2];
  int boff[2]; const short* bsrcp[2];
  #pragma unroll
  for (int j = 0; j < 2; ++j){
    int ch = t + 256 * j;
    int r = ch >> 3, c = ch & 7;
    aoff[j] = ch * 8;
    asrcp[j] = A + (size_t)(m0 + r) * K + 8 * (c ^ (r & 7));
    boff[j] = ch * 8;
    bsrcp[j] = Bt + (size_t)(n0 + r) * K + 8 * (c ^ (r & 7));
  }

  {
    short* ab = &Asm[0][0]; short* bb = &Bsm[0][0];
    #pragma unroll
    for (int j = 0; j < 2; ++j){ GLL16(asrcp[j], ab + aoff[j]); GLL16(bsrcp[j], bb + boff[j]); }
  }

  fx4 acc[2][2] = {};
  for (int ks = 0; ks < 8; ++ks){
    asm volatile("s_waitcnt vmcnt(0)" ::: "memory");
    __builtin_amdgcn_s_barrier();
    if (ks < 7){
      int nb = (ks + 1) & 1;
      short* ab = &Asm[nb][0]; short* bb = &Bsm[nb][0];
      int kk = (ks + 1) * 64;
      #pragma unroll
      for (int j = 0; j < 2; ++j){ GLL16(asrcp[j] + kk, ab + aoff[j]); GLL16(bsrcp[j] + kk, bb + boff[j]); }
    }
    int buf = ks & 1;
    s16x8 af[2][2], bf[2][2];
    #pragma unroll
    for (int mi = 0; mi < 2; ++mi){
      int row = wm * 32 + mi * 16 + lr;
      #pragma unroll
      for (int s = 0; s < 2; ++s)
        af[mi][s] = *(const s16x8*)&Asm[buf][row * 64 + ((4 * s + lg) ^ (row & 7)) * 8];
    }
    #pragma unroll
    for (int ni = 0; ni < 2; ++ni){
      int row = wn * 32 + ni * 16 + lr;
      #pragma unroll
      for (int s = 0; s < 2; ++s)
        bf[ni][s] = *(const s16x8*)&Bsm[buf][row * 64 + ((4 * s + lg) ^ (row & 7)) * 8];
    }
    __builtin_amdgcn_s_setprio(1);
    #pragma unroll
    for (int s = 0; s < 2; ++s)
      #pragma unroll
      for (int mi = 0; mi < 2; ++mi)
        #pragma unroll
        for (int ni = 0; ni < 2; ++ni)
          acc[mi][ni] = mfma16(af[mi][s], bf[ni][s], acc[mi][ni]);
    __builtin_amdgcn_s_setprio(0);
  }

  #pragma unroll
  for (int mi = 0; mi < 2; ++mi)
    #pragma unroll
    for (int ni = 0; ni < 2; ++ni)
      #pragma unroll
      for (int r = 0; r < 4; ++r){
        int row = m0 + wm * 32 + mi * 16 + 4 * lg + r;
        int col = n0 + wn * 32 + ni * 16 + lr;
        C[(size_t)row * DM + col] = acc[mi][ni][r];
      }
}

extern "C" void kernel_launch(void* const* d_in, const int* in_sizes, int n_in,
                              void* d_out, int out_size, void* d_ws, size_t ws_size,
                              hipStream_t stream) {
  const float* x     = (const float*)d_in[0];
  const float* Wq    = (const float*)d_in[1];
  const float* Wk    = (const float*)d_in[2];
  const float* Wv    = (const float*)d_in[3];
  const float* Wo    = (const float*)d_in[4];
  const float* labsK = (const float*)d_in[5];

  char* w = (char*)d_ws;
  short* Wt    = (short*)(w);                                  // 2 MB
  short* xeu   = (short*)(w + (2ull  << 20));                  // 4 MB
  short* Qs    = (short*)(w + (30ull << 20));                  // 4 MB
  short* Ks    = (short*)(w + (34ull << 20));                  // 4 MB
  short* Vt    = (short*)(w + (38ull << 20));                  // 4 MB
  float* Qt    = (float*)(w + (42ull << 20));                  // 128 KB
  float* Kt    = (float*)(w + (42ull << 20) + (128ull << 10)); // 128 KB
  short* Obf   = (short*)(w + (42ull << 20) + (256ull << 10)); // 4 MB
  float* Opart = (float*)(w + (48ull << 20));                  // 32 MB
  float* Mpart = (float*)(w + (80ull << 20));                  // 512 KB
  float* Lpart = (float*)(w + (81ull << 20));                  // 512 KB
  int*   cnt   = (int*)  (w + (82ull << 20));                  // 1 KB

  hipMemsetAsync(cnt, 0, 256 * sizeof(int), stream);

  prep_kernel<<<dim3(2304), 256, 0, stream>>>(Wq, Wk, Wv, Wo, Wt, x, xeu);

  gemm_fused_kernel<<<dim3(32, 8, 3), 256, 0, stream>>>(
      xeu, Wt, labsK, Qt, Qs, Kt, Ks, Vt);

  attn_kernel<<<dim3(640), 256, 0, stream>>>(
      Qs, Qt, Ks, Kt, Vt, Mpart, Lpart, Opart, cnt, Obf);

  gemm_o_kernel<<<dim3(64, 8), 256, 0, stream>>>(Obf, Wt + 3 * DM * DM, (float*)d_out);
}

// Round 7
// 65.864 us; speedup vs baseline: 3.2800x; 3.2800x over previous
//
#include <hip/hip_runtime.h>
#include <math.h>

#define S_LEN 2048
#define B_SZ 2
#define NH 8
#define DH 64
#define DM 512
#define MROWS 4096  // B*S

typedef __attribute__((ext_vector_type(8))) short s16x8;
typedef __attribute__((ext_vector_type(4))) float fx4;
typedef __attribute__((ext_vector_type(16))) float fx16;
typedef __attribute__((ext_vector_type(4))) int ix4;

__device__ inline short f2bf(float x){
  unsigned u = __float_as_uint(x);
  u = (u + 0x7FFFu + ((u >> 16) & 1u)) >> 16;
  return (short)u;
}

__device__ inline fx4 mfma16(s16x8 a, s16x8 b, fx4 c){
  return __builtin_amdgcn_mfma_f32_16x16x32_bf16(a, b, c, 0, 0, 0);
}
__device__ inline fx16 mfma32(s16x8 a, s16x8 b, fx16 c){
  return __builtin_amdgcn_mfma_f32_32x32x16_bf16(a, b, c, 0, 0, 0);
}
__device__ inline int cvtpk(float a, float b){
  int r; asm("v_cvt_pk_bf16_f32 %0, %1, %2" : "=v"(r) : "v"(a), "v"(b)); return r;
}

#define GLL16(g, l) __builtin_amdgcn_global_load_lds((const __attribute__((address_space(1))) void*)(g), (__attribute__((address_space(3))) void*)(l), 16, 0, 0)
#define GLL4(g, l)  __builtin_amdgcn_global_load_lds((const __attribute__((address_space(1))) void*)(g), (__attribute__((address_space(3))) void*)(l), 4, 0, 0)

// ---- K0: fused weight-transpose (blocks 0..255) + logmap (blocks 256..2303) ----
__global__ __launch_bounds__(256) void prep_kernel(const float* __restrict__ W0,
                                                   const float* __restrict__ W1,
                                                   const float* __restrict__ W2,
                                                   const float* __restrict__ W3,
                                                   short* __restrict__ Wt,
                                                   const float* __restrict__ x,
                                                   short* __restrict__ xeu){
  __shared__ short tile[64][66];
  __shared__ float s4[4];
  int bid = blockIdx.x;
  int t = threadIdx.x;
  if (bid < 256){
    int z = bid >> 6, rem = bid & 63;
    const float* W = (z == 0) ? W0 : (z == 1) ? W1 : (z == 2) ? W2 : W3;
    short* Wtz = Wt + (size_t)z * DM * DM;
    int n0 = (rem & 7) * 64, k0 = (rem >> 3) * 64;
    int nl = t & 63;
    #pragma unroll
    for (int p = 0; p < 16; ++p){
      int kl = (t >> 6) + p * 4;
      tile[kl][nl] = f2bf(W[(size_t)(k0 + kl) * DM + n0 + nl]);
    }
    __syncthreads();
    int kl2 = t & 63;
    #pragma unroll
    for (int p = 0; p < 16; ++p){
      int nl2 = (t >> 6) + p * 4;
      Wtz[(size_t)(n0 + nl2) * DM + k0 + kl2] = tile[kl2][nl2];
    }
  } else {
    int row = 2 * (bid - 256) + (t >> 7);
    int tl = t & 127;
    const float* xr = x + (size_t)row * (DM + 1);
    float v[4]; float ss = 0.f;
    #pragma unroll
    for (int j = 0; j < 4; ++j){
      v[j] = xr[1 + tl + 128 * j];
      ss += v[j] * v[j];
    }
    #pragma unroll
    for (int off = 1; off < 64; off <<= 1) ss += __shfl_xor(ss, off);
    if ((t & 63) == 0) s4[t >> 6] = ss;
    __syncthreads();
    int g2 = t >> 7;
    float tot = s4[2 * g2] + s4[2 * g2 + 1];
    float nrm = sqrtf(tot);
    float xt = xr[0];
    float theta = acoshf(fmaxf(xt, 1.0f + 1e-7f));
    float scl = theta / fmaxf(nrm, 1e-7f);
    #pragma unroll
    for (int j = 0; j < 4; ++j)
      xeu[(size_t)row * DM + tl + 128 * j] = f2bf(scl * v[j]);
  }
}

// ---- K2: QKV GEMM + fused exp-map / V-transpose. Single-barrier pipelined loop. ----
__global__ __launch_bounds__(256, 3) void gemm_fused_kernel(const short* __restrict__ A,
                                                            const short* __restrict__ Bt,
                                                            const float* __restrict__ labsK,
                                                            float* __restrict__ Qt,
                                                            short* __restrict__ Qs,
                                                            float* __restrict__ Kt,
                                                            short* __restrict__ Ks,
                                                            short* __restrict__ Vt){
  __shared__ __attribute__((aligned(16))) short Asm[2][128 * 64];
  __shared__ __attribute__((aligned(16))) short Bsm[2][64 * 64];
  __shared__ float nrm2s[2][128];
  const int K = DM;
  int z = blockIdx.z;
  int h = blockIdx.y;                 // head
  int n0 = h * 64, m0 = blockIdx.x * 128;
  int t = threadIdx.x;
  int w = t >> 6, lane = t & 63;
  int wm = w >> 1, wn = w & 1;
  int lg = lane >> 4, lr = lane & 15;
  const short* Btz = Bt + (size_t)z * K * DM;

  int aoff[4]; const short* asrcp[4];
  int boff[2]; const short* bsrcp[2];
  #pragma unroll
  for (int j = 0; j < 4; ++j){
    int ch = t + 256 * j;
    int r = ch >> 3, c = ch & 7;
    aoff[j] = ch * 8;
    asrcp[j] = A + (size_t)(m0 + r) * K + 8 * (c ^ (r & 7));
  }
  #pragma unroll
  for (int j = 0; j < 2; ++j){
    int ch = t + 256 * j;
    int r = ch >> 3, c = ch & 7;
    boff[j] = ch * 8;
    bsrcp[j] = Btz + (size_t)(n0 + r) * K + 8 * (c ^ (r & 7));
  }

  {
    short* ab = &Asm[0][0]; short* bb = &Bsm[0][0];
    #pragma unroll
    for (int j = 0; j < 4; ++j) GLL16(asrcp[j], ab + aoff[j]);
    #pragma unroll
    for (int j = 0; j < 2; ++j) GLL16(bsrcp[j], bb + boff[j]);
  }

  fx4 acc[4][2] = {};
  for (int ks = 0; ks < 8; ++ks){
    asm volatile("s_waitcnt vmcnt(0)" ::: "memory");
    __builtin_amdgcn_s_barrier();
    if (ks < 7){
      int nb = (ks + 1) & 1;
      short* ab = &Asm[nb][0]; short* bb = &Bsm[nb][0];
      int kk = (ks + 1) * 64;
      #pragma unroll
      for (int j = 0; j < 4; ++j) GLL16(asrcp[j] + kk, ab + aoff[j]);
      #pragma unroll
      for (int j = 0; j < 2; ++j) GLL16(bsrcp[j] + kk, bb + boff[j]);
    }
    int buf = ks & 1;
    s16x8 af[4][2], bf[2][2];
    #pragma unroll
    for (int mi = 0; mi < 4; ++mi){
      int row = wm * 64 + mi * 16 + lr;
      #pragma unroll
      for (int s = 0; s < 2; ++s)
        af[mi][s] = *(const s16x8*)&Asm[buf][row * 64 + ((4 * s + lg) ^ (row & 7)) * 8];
    }
    #pragma unroll
    for (int ni = 0; ni < 2; ++ni){
      int row = wn * 32 + ni * 16 + lr;
      #pragma unroll
      for (int s = 0; s < 2; ++s)
        bf[ni][s] = *(const s16x8*)&Bsm[buf][row * 64 + ((4 * s + lg) ^ (row & 7)) * 8];
    }
    __builtin_amdgcn_s_setprio(1);
    #pragma unroll
    for (int s = 0; s < 2; ++s)
      #pragma unroll
      for (int mi = 0; mi < 4; ++mi)
        #pragma unroll
        for (int ni = 0; ni < 2; ++ni)
          acc[mi][ni] = mfma16(af[mi][s], bf[ni][s], acc[mi][ni]);
    __builtin_amdgcn_s_setprio(0);
  }

  if (z < 2){
    #pragma unroll
    for (int mi = 0; mi < 4; ++mi)
      #pragma unroll
      for (int r = 0; r < 4; ++r){
        float prt = acc[mi][0][r] * acc[mi][0][r] + acc[mi][1][r] * acc[mi][1][r];
        prt += __shfl_xor(prt, 1);
        prt += __shfl_xor(prt, 2);
        prt += __shfl_xor(prt, 4);
        prt += __shfl_xor(prt, 8);
        if (lr == 0) nrm2s[wn][wm * 64 + mi * 16 + 4 * lg + r] = prt;
      }
    __syncthreads();
    float c  = __expf(labsK[h]);
    float sc = sqrtf(c);
    float invsc = __frcp_rn(sc);
    float a  = 0.125f * c * 1.4426950408889634f;
    float tmul = (z == 0) ? a : 1.0f;
    float vmul = (z == 0) ? -a : 1.0f;
    float* Tt = (z == 0) ? Qt : Kt;
    short* Ts = (z == 0) ? Qs : Ks;
    #pragma unroll
    for (int mi = 0; mi < 4; ++mi)
      #pragma unroll
      for (int r = 0; r < 4; ++r){
        int row_local = wm * 64 + mi * 16 + 4 * lg + r;
        float full = nrm2s[0][row_local] + nrm2s[1][row_local];
        float n = fmaxf(sqrtf(full), 1e-7f);
        float arg = sc * n;
        float e = __expf(arg), ei = __frcp_rn(e);
        float tval = tmul * 0.5f * (e + ei) * invsc;
        float vscl = vmul * 0.5f * (e - ei) * __frcp_rn(arg);
        int grow = m0 + row_local;
        int b = grow >> 11, s = grow & (S_LEN - 1);
        size_t bhs = ((size_t)(b * NH + h) * S_LEN + s);
        if (lr == 0) Tt[bhs] = tval;
        #pragma unroll
        for (int ni = 0; ni < 2; ++ni)
          Ts[bhs * DH + wn * 32 + ni * 16 + lr] = f2bf(vscl * acc[mi][ni][r]);
      }
  } else {
    short* vt = (short*)&Asm[0][0];
    __syncthreads();
    #pragma unroll
    for (int mi = 0; mi < 4; ++mi)
      #pragma unroll
      for (int ni = 0; ni < 2; ++ni)
        #pragma unroll
        for (int r = 0; r < 4; ++r){
          int row_local = wm * 64 + mi * 16 + 4 * lg + r;
          int col_local = wn * 32 + ni * 16 + lr;
          vt[col_local * 136 + row_local] = f2bf(acc[mi][ni][r]);
        }
    __syncthreads();
    int d = t >> 2, sseg = (t & 3) * 32;
    int b = m0 >> 11;
    size_t vbase = ((size_t)(b * NH + h) * DH + d) * S_LEN + (m0 & (S_LEN - 1)) + sseg;
    #pragma unroll
    for (int j = 0; j < 4; ++j){
      s16x8 val = *(const s16x8*)&vt[d * 136 + sseg + 8 * j];
      *(s16x8*)(Vt + vbase + 8 * j) = val;
    }
  }
}

// ---- K4: flash attention, key-split chunks, 3-buffer ring + counted vmcnt,
//      single barrier/tile. Partials only — no fences/atomics (XCD L2 coherence
//      is provided by the kernel boundary before combine_kernel). ----
__global__ __launch_bounds__(256, 3) void attn_kernel(const short* __restrict__ Qs,
                                                      const float* __restrict__ Qt,
                                                      const short* __restrict__ Ks,
                                                      const float* __restrict__ Kt,
                                                      const short* __restrict__ Vt,
                                                      float* __restrict__ Mpart,
                                                      float* __restrict__ Lpart,
                                                      float* __restrict__ Opart){
  __shared__ __attribute__((aligned(16))) short Ksm[3][4096];
  __shared__ __attribute__((aligned(16))) short Vsm[3][4096];
  __shared__ __attribute__((aligned(16))) float Ktm[3][64];

  int bx = blockIdx.x;
  int bh = bx & 15;                 // XCD-local heads
  int id = bx >> 4;                 // 0..39
  int g, c;
  if (id < 4)       { g = id;                 c = 0; }
  else if (id < 12) { g = 4 + ((id - 4) >> 1);  c = (id - 4) & 1; }
  else if (id < 24) { int r = id - 12; int q3 = r / 3; g = 8 + q3; c = r - 3 * q3; }
  else              { g = 12 + ((id - 24) >> 2); c = (id - 24) & 3; }
  int kbeg = 512 * c;
  int kend = 512 * c + 512; { int ge = 128 * g + 128; if (ge < kend) kend = ge; }
  int ntc = (kend - kbeg) >> 6;

  int tid = threadIdx.x;
  int w = tid >> 6, lane = tid & 63;
  int l5 = lane & 31, hi = lane >> 5;
  size_t bhS = (size_t)bh * S_LEN;

  const short* Kg  = Ks + bhS * DH;
  const short* Vg  = Vt + (size_t)bh * DH * S_LEN;
  const float* Ktg = Kt + bhS;

  int srow = lane >> 3;
  int scol = ((lane & 7) * 8) ^ (srow << 3);
  const short* kg0 = Kg + (size_t)(kbeg + 16 * w + srow) * DH + scol;
  const short* kg1 = kg0 + 8 * DH;
  const short* vg0 = Vg + (size_t)(16 * w + srow) * S_LEN + kbeg + scol;
  const short* vg1 = vg0 + 8 * S_LEN;
  const float* ktg = Ktg + kbeg + lane;

  int q0w = 128 * g + 32 * w;
  int q   = q0w + l5;
  int qmax = q0w + 31;
  s16x8 qf[4];
  #pragma unroll
  for (int dblk = 0; dblk < 4; ++dblk)
    qf[dblk] = *(const s16x8*)(Qs + (bhS + q) * DH + dblk * 16 + hi * 8);
  float aqt = Qt[bhS + q];

  fx16 acc0, acc1;
  #pragma unroll
  for (int i = 0; i < 16; ++i){ acc0[i] = 0.f; acc1[i] = 0.f; }
  float mrun = 0.f, lrun = 0.f;

  #define STAGE_T(tt, b) { int off_ = (tt) * 64; \
    GLL16(kg0 + (size_t)off_ * DH, &Ksm[b][16 * w * 64]); \
    GLL16(kg1 + (size_t)off_ * DH, &Ksm[b][16 * w * 64 + 512]); \
    GLL16(vg0 + off_, &Vsm[b][16 * w * 64]); \
    GLL16(vg1 + off_, &Vsm[b][16 * w * 64 + 512]); \
    if (w == 3) GLL4(ktg + off_, &Ktm[b][0]); }

  STAGE_T(0, 0);
  if (ntc > 1) STAGE_T(1, 1);

  int buf = 0, sbuf = 2;
  for (int t = 0; t < ntc; ++t){
    int k0 = kbeg + t * 64;
    if (t + 1 < ntc){
      if (w == 3) asm volatile("s_waitcnt vmcnt(5)" ::: "memory");
      else        asm volatile("s_waitcnt vmcnt(4)" ::: "memory");
    } else {
      asm volatile("s_waitcnt vmcnt(0)" ::: "memory");
    }
    __builtin_amdgcn_s_barrier();
    if (t + 2 < ntc) STAGE_T(t + 2, sbuf);

    if (k0 <= qmax){
      fx16 st[2];
      __builtin_amdgcn_s_setprio(1);
      #pragma unroll
      for (int s = 0; s < 2; ++s){
        const short* kb = &Ksm[buf][(32 * s + l5) * 64];
        fx16 z;
        #pragma unroll
        for (int i = 0; i < 16; ++i) z[i] = 0.f;
        #pragma unroll
        for (int dblk = 0; dblk < 4; ++dblk){
          s16x8 kf = *(const s16x8*)(kb + ((16 * dblk + 8 * hi) ^ ((l5 & 7) << 3)));
          z = mfma32(kf, qf[dblk], z);
        }
        st[s] = z;
      }
      __builtin_amdgcn_s_setprio(0);
      float p[2][16];
      #pragma unroll
      for (int s = 0; s < 2; ++s)
        #pragma unroll
        for (int m4 = 0; m4 < 4; ++m4){
          fx4 kt4 = *(const fx4*)&Ktm[buf][32 * s + 8 * m4 + 4 * hi];
          #pragma unroll
          for (int tt = 0; tt < 4; ++tt)
            p[s][4 * m4 + tt] = st[s][4 * m4 + tt] + aqt * kt4[tt];
        }
      if (k0 + 63 > q0w){
        #pragma unroll
        for (int s = 0; s < 2; ++s)
          #pragma unroll
          for (int r = 0; r < 16; ++r){
            int kg2 = k0 + 32 * s + (r & 3) + 8 * (r >> 2) + 4 * hi;
            if (kg2 > q) p[s][r] = -3e38f;
          }
      }
      float v16[16];
      #pragma unroll
      for (int i = 0; i < 16; ++i) v16[i] = fmaxf(p[0][i], p[1][i]);
      #pragma unroll
      for (int i = 0; i < 8; ++i) v16[i] = fmaxf(v16[i], v16[i + 8]);
      #pragma unroll
      for (int i = 0; i < 4; ++i) v16[i] = fmaxf(v16[i], v16[i + 4]);
      float pmax = fmaxf(fmaxf(v16[0], v16[1]), fmaxf(v16[2], v16[3]));
      pmax = fmaxf(pmax, __shfl_xor(pmax, 32));
      if (!__all(pmax <= mrun + 8.f)){
        float mnew = fmaxf(mrun, pmax);
        float scl = __builtin_amdgcn_exp2f(mrun - mnew);
        mrun = mnew;
        lrun *= scl;
        #pragma unroll
        for (int i = 0; i < 16; ++i){ acc0[i] *= scl; acc1[i] *= scl; }
      }
      float sm[16];
      #pragma unroll
      for (int i = 0; i < 16; ++i){
        p[0][i] = __builtin_amdgcn_exp2f(p[0][i] - mrun);
        p[1][i] = __builtin_amdgcn_exp2f(p[1][i] - mrun);
        sm[i] = p[0][i] + p[1][i];
      }
      #pragma unroll
      for (int i = 0; i < 8; ++i) sm[i] += sm[i + 8];
      #pragma unroll
      for (int i = 0; i < 4; ++i) sm[i] += sm[i + 4];
      float rsum = (sm[0] + sm[1]) + (sm[2] + sm[3]);
      rsum += __shfl_xor(rsum, 32);
      lrun += rsum;

      #pragma unroll
      for (int h = 0; h < 4; ++h){
        int s = h >> 1, hb = h & 1;
        int w0 = cvtpk(p[s][8 * hb + 0], p[s][8 * hb + 1]);
        int w1 = cvtpk(p[s][8 * hb + 2], p[s][8 * hb + 3]);
        int w2 = cvtpk(p[s][8 * hb + 4], p[s][8 * hb + 5]);
        int w3 = cvtpk(p[s][8 * hb + 6], p[s][8 * hb + 7]);
        int sdA = hi ? w0 : w2;
        int sdB = hi ? w1 : w3;
        int rcA = __shfl_xor(sdA, 32);
        int rcB = __shfl_xor(sdB, 32);
        ix4 fw;
        fw.x = hi ? rcA : w0; fw.y = hi ? rcB : w1;
        fw.z = hi ? w2 : rcA; fw.w = hi ? w3 : rcB;
        s16x8 pf = __builtin_bit_cast(s16x8, fw);
        const short* vb0 = &Vsm[buf][(l5) * 64 + ((16 * h + 8 * hi) ^ ((l5 & 7) << 3))];
        const short* vb1 = vb0 + 32 * 64;
        s16x8 vf0 = *(const s16x8*)vb0;
        s16x8 vf1 = *(const s16x8*)vb1;
        __builtin_amdgcn_s_setprio(1);
        acc0 = mfma32(vf0, pf, acc0);
        acc1 = mfma32(vf1, pf, acc1);
        __builtin_amdgcn_s_setprio(0);
      }
    }
    buf  = (buf == 2)  ? 0 : buf + 1;
    sbuf = (sbuf == 2) ? 0 : sbuf + 1;
  }

  // ---- store partials: [q within 128][64 d] f32, plus m/l per q ----
  int slot = ((bh << 4) + g) * 4 + c;
  int qi = 32 * w + l5;
  if (hi == 0){
    Mpart[(size_t)slot * 128 + qi] = mrun;
    Lpart[(size_t)slot * 128 + qi] = lrun;
  }
  float* Op = Opart + (size_t)slot * 8192 + (size_t)qi * 64;
  #pragma unroll
  for (int j = 0; j < 4; ++j){
    fx4 v0, v1;
    #pragma unroll
    for (int i = 0; i < 4; ++i){ v0[i] = acc0[4 * j + i]; v1[i] = acc1[4 * j + i]; }
    *(fx4*)(Op + 8 * j + 4 * hi)      = v0;
    *(fx4*)(Op + 32 + 8 * j + 4 * hi) = v1;
  }
}

// ---- K4b: combine partials -> Obf bf16. 1024 blocks, oct-fast coalesced reads ----
__global__ __launch_bounds__(256) void combine_kernel(const float* __restrict__ Mpart,
                                                      const float* __restrict__ Lpart,
                                                      const float* __restrict__ Opart,
                                                      short* __restrict__ Obf){
  int bx = blockIdx.x;
  int bhg = bx & 255;
  int bh = bhg & 15, g = bhg >> 4;
  int qq = bx >> 8;                  // 0..3
  int t = threadIdx.x;
  int q = qq * 32 + (t >> 3);        // q within 128-group
  int oct = t & 7;                   // 8-d octet
  int nch = (g >> 2) + 1;
  int gbase = ((bh << 4) + g) * 4;

  float mc[4], lc[4];
  #pragma unroll
  for (int c = 0; c < 4; ++c){
    mc[c] = Mpart[(size_t)(gbase + c) * 128 + q];
    lc[c] = Lpart[(size_t)(gbase + c) * 128 + q];
    if (c >= nch) mc[c] = -3e38f;    // weight 0 via exp2
  }
  float M = fmaxf(fmaxf(mc[0], mc[1]), fmaxf(mc[2], mc[3]));
  float wc[4]; float L = 0.f;
  #pragma unroll
  for (int c = 0; c < 4; ++c){
    wc[c] = __builtin_amdgcn_exp2f(mc[c] - M);
    L += wc[c] * lc[c];
  }
  float invL = 1.f / L;
  #pragma unroll
  for (int c = 0; c < 4; ++c) wc[c] *= invL;

  const float* ob = Opart + (size_t)gbase * 8192 + (size_t)q * 64 + oct * 8;
  float accf[8] = {0.f,0.f,0.f,0.f,0.f,0.f,0.f,0.f};
  #pragma unroll
  for (int c = 0; c < 4; ++c){
    fx4 a = *(const fx4*)(ob + (size_t)c * 8192);
    fx4 b = *(const fx4*)(ob + (size_t)c * 8192 + 4);
    #pragma unroll
    for (int k = 0; k < 4; ++k){ accf[k] += wc[c] * a[k]; accf[4 + k] += wc[c] * b[k]; }
  }
  s16x8 pk;
  #pragma unroll
  for (int dd = 0; dd < 8; ++dd) pk[dd] = f2bf(accf[dd]);
  int bb = bh >> 3, hh = bh & 7;
  *(s16x8*)(Obf + ((size_t)bb * S_LEN + 128 * g + q) * DM + hh * DH + oct * 8) = pk;
}

// ---- K5: O-projection GEMM, 64x64 tiles, single-barrier loop ----
__global__ __launch_bounds__(256, 4) void gemm_o_kernel(const short* __restrict__ A,
                                                        const short* __restrict__ Bt,
                                                        float* __restrict__ C){
  __shared__ __attribute__((aligned(16))) short Asm[2][64 * 64];
  __shared__ __attribute__((aligned(16))) short Bsm[2][64 * 64];
  const int K = DM;
  int n0 = blockIdx.y * 64, m0 = blockIdx.x * 64;
  int t = threadIdx.x;
  int w = t >> 6, lane = t & 63;
  int wm = w >> 1, wn = w & 1;
  int lg = lane >> 4, lr = lane & 15;

  int aoff[2]; const short* asrcp[2];
  int boff[2]; const short* bsrcp[2];
  #pragma unroll
  for (int j = 0; j < 2; ++j){
    int ch = t + 256 * j;
    int r = ch >> 3, c = ch & 7;
    aoff[j] = ch * 8;
    asrcp[j] = A + (size_t)(m0 + r) * K + 8 * (c ^ (r & 7));
    boff[j] = ch * 8;
    bsrcp[j] = Bt + (size_t)(n0 + r) * K + 8 * (c ^ (r & 7));
  }

  {
    short* ab = &Asm[0][0]; short* bb = &Bsm[0][0];
    #pragma unroll
    for (int j = 0; j < 2; ++j){ GLL16(asrcp[j], ab + aoff[j]); GLL16(bsrcp[j], bb + boff[j]); }
  }

  fx4 acc[2][2] = {};
  for (int ks = 0; ks < 8; ++ks){
    asm volatile("s_waitcnt vmcnt(0)" ::: "memory");
    __builtin_amdgcn_s_barrier();
    if (ks < 7){
      int nb = (ks + 1) & 1;
      short* ab = &Asm[nb][0]; short* bb = &Bsm[nb][0];
      int kk = (ks + 1) * 64;
      #pragma unroll
      for (int j = 0; j < 2; ++j){ GLL16(asrcp[j] + kk, ab + aoff[j]); GLL16(bsrcp[j] + kk, bb + boff[j]); }
    }
    int buf = ks & 1;
    s16x8 af[2][2], bf[2][2];
    #pragma unroll
    for (int mi = 0; mi < 2; ++mi){
      int row = wm * 32 + mi * 16 + lr;
      #pragma unroll
      for (int s = 0; s < 2; ++s)
        af[mi][s] = *(const s16x8*)&Asm[buf][row * 64 + ((4 * s + lg) ^ (row & 7)) * 8];
    }
    #pragma unroll
    for (int ni = 0; ni < 2; ++ni){
      int row = wn * 32 + ni * 16 + lr;
      #pragma unroll
      for (int s = 0; s < 2; ++s)
        bf[ni][s] = *(const s16x8*)&Bsm[buf][row * 64 + ((4 * s + lg) ^ (row & 7)) * 8];
    }
    __builtin_amdgcn_s_setprio(1);
    #pragma unroll
    for (int s = 0; s < 2; ++s)
      #pragma unroll
      for (int mi = 0; mi < 2; ++mi)
        #pragma unroll
        for (int ni = 0; ni < 2; ++ni)
          acc[mi][ni] = mfma16(af[mi][s], bf[ni][s], acc[mi][ni]);
    __builtin_amdgcn_s_setprio(0);
  }

  #pragma unroll
  for (int mi = 0; mi < 2; ++mi)
    #pragma unroll
    for (int ni = 0; ni < 2; ++ni)
      #pragma unroll
      for (int r = 0; r < 4; ++r){
        int row = m0 + wm * 32 + mi * 16 + 4 * lg + r;
        int col = n0 + wn * 32 + ni * 16 + lr;
        C[(size_t)row * DM + col] = acc[mi][ni][r];
      }
}

extern "C" void kernel_launch(void* const* d_in, const int* in_sizes, int n_in,
                              void* d_out, int out_size, void* d_ws, size_t ws_size,
                              hipStream_t stream) {
  const float* x     = (const float*)d_in[0];
  const float* Wq    = (const float*)d_in[1];
  const float* Wk    = (const float*)d_in[2];
  const float* Wv    = (const float*)d_in[3];
  const float* Wo    = (const float*)d_in[4];
  const float* labsK = (const float*)d_in[5];

  char* w = (char*)d_ws;
  short* Wt    = (short*)(w);                                  // 2 MB
  short* xeu   = (short*)(w + (2ull  << 20));                  // 4 MB
  short* Qs    = (short*)(w + (30ull << 20));                  // 4 MB
  short* Ks    = (short*)(w + (34ull << 20));                  // 4 MB
  short* Vt    = (short*)(w + (38ull << 20));                  // 4 MB
  float* Qt    = (float*)(w + (42ull << 20));                  // 128 KB
  float* Kt    = (float*)(w + (42ull << 20) + (128ull << 10)); // 128 KB
  short* Obf   = (short*)(w + (42ull << 20) + (256ull << 10)); // 4 MB
  float* Opart = (float*)(w + (48ull << 20));                  // 32 MB
  float* Mpart = (float*)(w + (80ull << 20));                  // 512 KB
  float* Lpart = (float*)(w + (81ull << 20));                  // 512 KB

  prep_kernel<<<dim3(2304), 256, 0, stream>>>(Wq, Wk, Wv, Wo, Wt, x, xeu);

  gemm_fused_kernel<<<dim3(32, 8, 3), 256, 0, stream>>>(
      xeu, Wt, labsK, Qt, Qs, Kt, Ks, Vt);

  attn_kernel<<<dim3(640), 256, 0, stream>>>(
      Qs, Qt, Ks, Kt, Vt, Mpart, Lpart, Opart);

  combine_kernel<<<dim3(1024), 256, 0, stream>>>(Mpart, Lpart, Opart, Obf);

  gemm_o_kernel<<<dim3(64, 8), 256, 0, stream>>>(Obf, Wt + 3 * DM * DM, (float*)d_out);
}

// Round 8
// 59.856 us; speedup vs baseline: 3.6092x; 1.1004x over previous
//
#include <hip/hip_runtime.h>
#include <math.h>

#define S_LEN 2048
#define B_SZ 2
#define NH 8
#define DH 64
#define DM 512
#define MROWS 4096  // B*S

typedef __attribute__((ext_vector_type(8))) short s16x8;
typedef __attribute__((ext_vector_type(4))) float fx4;
typedef __attribute__((ext_vector_type(16))) float fx16;
typedef __attribute__((ext_vector_type(4))) int ix4;
typedef __attribute__((ext_vector_type(2))) int ix2;

__device__ inline short f2bf(float x){
  unsigned u = __float_as_uint(x);
  u = (u + 0x7FFFu + ((u >> 16) & 1u)) >> 16;
  return (short)u;
}
__device__ inline float bf2f(short s){
  return __uint_as_float(((unsigned)(unsigned short)s) << 16);
}

__device__ inline fx4 mfma16(s16x8 a, s16x8 b, fx4 c){
  return __builtin_amdgcn_mfma_f32_16x16x32_bf16(a, b, c, 0, 0, 0);
}
__device__ inline fx16 mfma32(s16x8 a, s16x8 b, fx16 c){
  return __builtin_amdgcn_mfma_f32_32x32x16_bf16(a, b, c, 0, 0, 0);
}
__device__ inline int cvtpk(float a, float b){
  int r; asm("v_cvt_pk_bf16_f32 %0, %1, %2" : "=v"(r) : "v"(a), "v"(b)); return r;
}

#define GLL16(g, l) __builtin_amdgcn_global_load_lds((const __attribute__((address_space(1))) void*)(g), (__attribute__((address_space(3))) void*)(l), 16, 0, 0)
#define GLL4(g, l)  __builtin_amdgcn_global_load_lds((const __attribute__((address_space(1))) void*)(g), (__attribute__((address_space(3))) void*)(l), 4, 0, 0)

// ---- K0: fused weight-transpose (blocks 0..255) + logmap (blocks 256..1279) ----
__global__ __launch_bounds__(256) void prep_kernel(const float* __restrict__ W0,
                                                   const float* __restrict__ W1,
                                                   const float* __restrict__ W2,
                                                   const float* __restrict__ W3,
                                                   short* __restrict__ Wt,
                                                   const float* __restrict__ x,
                                                   short* __restrict__ xeu){
  __shared__ short tile[64][66];
  int bid = blockIdx.x;
  int t = threadIdx.x;
  if (bid < 256){
    int z = bid >> 6, rem = bid & 63;
    const float* W = (z == 0) ? W0 : (z == 1) ? W1 : (z == 2) ? W2 : W3;
    short* Wtz = Wt + (size_t)z * DM * DM;
    int n0 = (rem & 7) * 64, k0 = (rem >> 3) * 64;
    int nl = t & 63;
    #pragma unroll
    for (int p = 0; p < 16; ++p){
      int kl = (t >> 6) + p * 4;
      tile[kl][nl] = f2bf(W[(size_t)(k0 + kl) * DM + n0 + nl]);
    }
    __syncthreads();
    int kl2 = t & 63;
    #pragma unroll
    for (int p = 0; p < 16; ++p){
      int nl2 = (t >> 6) + p * 4;
      Wtz[(size_t)(n0 + nl2) * DM + k0 + kl2] = tile[kl2][nl2];
    }
  } else {
    // wave-per-row logmap: 4 rows/block
    int row = (bid - 256) * 4 + (t >> 6);
    int lane = t & 63;
    const float* xr = x + (size_t)row * (DM + 1);
    float v[8]; float ss = 0.f;
    #pragma unroll
    for (int j = 0; j < 8; ++j){
      v[j] = xr[1 + lane * 8 + j];
      ss += v[j] * v[j];
    }
    #pragma unroll
    for (int off = 1; off < 64; off <<= 1) ss += __shfl_xor(ss, off);
    float nrm = sqrtf(ss);
    float xt = xr[0];
    float theta = acoshf(fmaxf(xt, 1.0f + 1e-7f));
    float scl = theta / fmaxf(nrm, 1e-7f);
    s16x8 pk;
    #pragma unroll
    for (int j = 0; j < 8; ++j) pk[j] = f2bf(scl * v[j]);
    *(s16x8*)(xeu + (size_t)row * DM + lane * 8) = pk;
  }
}

// ---- K2: QKV GEMM 128x128 tiles (wave = one head) + fused exp-map / V-transpose ----
// grid (32 m-tiles, 4 head-pairs, 3 z). 4 waves 2x2, each 64x64. LDS 64 KB.
__global__ __launch_bounds__(256, 2) void gemm_fused_kernel(const short* __restrict__ A,
                                                            const short* __restrict__ Bt,
                                                            const float* __restrict__ labsK,
                                                            float* __restrict__ Qt,
                                                            short* __restrict__ Qs,
                                                            float* __restrict__ Kt,
                                                            short* __restrict__ Ks,
                                                            short* __restrict__ Vt){
  __shared__ __attribute__((aligned(16))) short Stage[4][8192]; // [0..1]=A, [2..3]=B
  const int K = DM;
  int z = blockIdx.z;
  int hp = blockIdx.y;                // head pair
  int n0 = hp * 128, m0 = blockIdx.x * 128;
  int t = threadIdx.x;
  int w = t >> 6, lane = t & 63;
  int wm = w >> 1, wn = w & 1;
  int lg = lane >> 4, lr = lane & 15;
  const short* Btz = Bt + (size_t)z * K * DM;

  int coff[4]; const short* asrcp[4]; const short* bsrcp[4];
  #pragma unroll
  for (int j = 0; j < 4; ++j){
    int ch = t + 256 * j;             // 0..1023
    int r = ch >> 3, c = ch & 7;
    coff[j] = ch * 8;
    asrcp[j] = A   + (size_t)(m0 + r) * K + 8 * (c ^ (r & 7));
    bsrcp[j] = Btz + (size_t)(n0 + r) * K + 8 * (c ^ (r & 7));
  }

  #pragma unroll
  for (int j = 0; j < 4; ++j){
    GLL16(asrcp[j], &Stage[0][coff[j]]);
    GLL16(bsrcp[j], &Stage[2][coff[j]]);
  }

  fx4 acc[4][4] = {};
  for (int ks = 0; ks < 4; ++ks){     // 4 iters x (2 k-steps worth? no: 8 steps)
    ; // placeholder removed below
    break;
  }
  for (int ks = 0; ks < 8; ++ks){
    asm volatile("s_waitcnt vmcnt(0)" ::: "memory");
    __builtin_amdgcn_s_barrier();
    if (ks < 7){
      int nb = (ks + 1) & 1;
      int kk = (ks + 1) * 64;
      #pragma unroll
      for (int j = 0; j < 4; ++j){
        GLL16(asrcp[j] + kk, &Stage[nb][coff[j]]);
        GLL16(bsrcp[j] + kk, &Stage[2 + nb][coff[j]]);
      }
    }
    int buf = ks & 1;
    s16x8 af[4][2], bf[4][2];
    #pragma unroll
    for (int mi = 0; mi < 4; ++mi){
      int row = wm * 64 + mi * 16 + lr;
      #pragma unroll
      for (int s = 0; s < 2; ++s)
        af[mi][s] = *(const s16x8*)&Stage[buf][row * 64 + ((4 * s + lg) ^ (row & 7)) * 8];
    }
    #pragma unroll
    for (int ni = 0; ni < 4; ++ni){
      int row = wn * 64 + ni * 16 + lr;
      #pragma unroll
      for (int s = 0; s < 2; ++s)
        bf[ni][s] = *(const s16x8*)&Stage[2 + buf][row * 64 + ((4 * s + lg) ^ (row & 7)) * 8];
    }
    __builtin_amdgcn_s_setprio(1);
    #pragma unroll
    for (int s = 0; s < 2; ++s)
      #pragma unroll
      for (int mi = 0; mi < 4; ++mi)
        #pragma unroll
        for (int ni = 0; ni < 4; ++ni)
          acc[mi][ni] = mfma16(af[mi][s], bf[ni][s], acc[mi][ni]);
    __builtin_amdgcn_s_setprio(0);
  }

  int h = hp * 2 + wn;                // this wave's head
  if (z < 2){
    // ---- wave-local exp-map epilogue (Q or K) ----
    float c  = __expf(labsK[h]);
    float sc = sqrtf(c);
    float invsc = __frcp_rn(sc);
    float a  = 0.125f * c * 1.4426950408889634f;
    float tmul = (z == 0) ? a : 1.0f;
    float vmul = (z == 0) ? -a : 1.0f;
    float* Tt = (z == 0) ? Qt : Kt;
    short* Ts = (z == 0) ? Qs : Ks;
    #pragma unroll
    for (int mi = 0; mi < 4; ++mi)
      #pragma unroll
      for (int r = 0; r < 4; ++r){
        float prt = 0.f;
        #pragma unroll
        for (int ni = 0; ni < 4; ++ni) prt += acc[mi][ni][r] * acc[mi][ni][r];
        prt += __shfl_xor(prt, 1);
        prt += __shfl_xor(prt, 2);
        prt += __shfl_xor(prt, 4);
        prt += __shfl_xor(prt, 8);
        float n = fmaxf(sqrtf(prt), 1e-7f);
        float arg = sc * n;
        float e = __expf(arg), ei = __frcp_rn(e);
        float tval = tmul * 0.5f * (e + ei) * invsc;
        float vscl = vmul * 0.5f * (e - ei) * __frcp_rn(arg);
        int grow = m0 + wm * 64 + mi * 16 + 4 * lg + r;
        int b = grow >> 11, s = grow & (S_LEN - 1);
        size_t bhs = ((size_t)(b * NH + h) * S_LEN + s);
        if (lr == 0) Tt[bhs] = tval;
        #pragma unroll
        for (int ni = 0; ni < 4; ++ni)
          Ts[bhs * DH + ni * 16 + lr] = f2bf(vscl * acc[mi][ni][r]);
      }
  } else {
    // ---- wave-local V transpose: acc -> LDS [64 d][68 pad] -> Vt (bh,d,s) bf16 ----
    __syncthreads();                  // all waves done reading Stage
    short* vt = &Stage[0][0] + w * 4352;
    #pragma unroll
    for (int mi = 0; mi < 4; ++mi)
      #pragma unroll
      for (int ni = 0; ni < 4; ++ni)
        #pragma unroll
        for (int r = 0; r < 4; ++r)
          vt[(ni * 16 + lr) * 68 + mi * 16 + 4 * lg + r] = f2bf(acc[mi][ni][r]);
    int b = m0 >> 11;
    int sglob = (m0 & (S_LEN - 1)) + wm * 64;
    size_t vbase = ((size_t)(b * NH + h) * DH + lane) * S_LEN + sglob;
    #pragma unroll
    for (int j = 0; j < 8; ++j){
      s16x8 val = *(const s16x8*)&vt[lane * 68 + j * 8];
      *(s16x8*)(Vt + vbase + j * 8) = val;
    }
  }
}

// ---- K4: flash attention, key-split chunks, 3-buffer ring + counted vmcnt.
// Single-chunk groups (g<4) write Obf directly; others write normalized bf16 partials. ----
__global__ __launch_bounds__(256, 3) void attn_kernel(const short* __restrict__ Qs,
                                                      const float* __restrict__ Qt,
                                                      const short* __restrict__ Ks,
                                                      const float* __restrict__ Kt,
                                                      const short* __restrict__ Vt,
                                                      float* __restrict__ Mpart,
                                                      float* __restrict__ Lpart,
                                                      short* __restrict__ Obn,
                                                      short* __restrict__ Obf){
  __shared__ __attribute__((aligned(16))) short Ksm[3][4096];
  __shared__ __attribute__((aligned(16))) short Vsm[3][4096];
  __shared__ __attribute__((aligned(16))) float Ktm[3][64];

  int bx = blockIdx.x;
  int bh = bx & 15;
  int id = bx >> 4;                 // 0..39
  int g, c;
  if (id < 4)       { g = id;                 c = 0; }
  else if (id < 12) { g = 4 + ((id - 4) >> 1);  c = (id - 4) & 1; }
  else if (id < 24) { int r = id - 12; int q3 = r / 3; g = 8 + q3; c = r - 3 * q3; }
  else              { g = 12 + ((id - 24) >> 2); c = (id - 24) & 3; }
  int nch = (g >> 2) + 1;
  int kbeg = 512 * c;
  int kend = 512 * c + 512; { int ge = 128 * g + 128; if (ge < kend) kend = ge; }
  int ntc = (kend - kbeg) >> 6;

  int tid = threadIdx.x;
  int w = tid >> 6, lane = tid & 63;
  int l5 = lane & 31, hi = lane >> 5;
  size_t bhS = (size_t)bh * S_LEN;

  const short* Kg  = Ks + bhS * DH;
  const short* Vg  = Vt + (size_t)bh * DH * S_LEN;
  const float* Ktg = Kt + bhS;

  int srow = lane >> 3;
  int scol = ((lane & 7) * 8) ^ (srow << 3);
  const short* kg0 = Kg + (size_t)(kbeg + 16 * w + srow) * DH + scol;
  const short* kg1 = kg0 + 8 * DH;
  const short* vg0 = Vg + (size_t)(16 * w + srow) * S_LEN + kbeg + scol;
  const short* vg1 = vg0 + 8 * S_LEN;
  const float* ktg = Ktg + kbeg + lane;

  int q0w = 128 * g + 32 * w;
  int q   = q0w + l5;
  int qmax = q0w + 31;
  s16x8 qf[4];
  #pragma unroll
  for (int dblk = 0; dblk < 4; ++dblk)
    qf[dblk] = *(const s16x8*)(Qs + (bhS + q) * DH + dblk * 16 + hi * 8);
  float aqt = Qt[bhS + q];

  fx16 acc0, acc1;
  #pragma unroll
  for (int i = 0; i < 16; ++i){ acc0[i] = 0.f; acc1[i] = 0.f; }
  float mrun = 0.f, lrun = 0.f;

  #define STAGE_T(tt, b) { int off_ = (tt) * 64; \
    GLL16(kg0 + (size_t)off_ * DH, &Ksm[b][16 * w * 64]); \
    GLL16(kg1 + (size_t)off_ * DH, &Ksm[b][16 * w * 64 + 512]); \
    GLL16(vg0 + off_, &Vsm[b][16 * w * 64]); \
    GLL16(vg1 + off_, &Vsm[b][16 * w * 64 + 512]); \
    if (w == 3) GLL4(ktg + off_, &Ktm[b][0]); }

  STAGE_T(0, 0);
  if (ntc > 1) STAGE_T(1, 1);

  int buf = 0, sbuf = 2;
  for (int t = 0; t < ntc; ++t){
    int k0 = kbeg + t * 64;
    if (t + 1 < ntc){
      if (w == 3) asm volatile("s_waitcnt vmcnt(5)" ::: "memory");
      else        asm volatile("s_waitcnt vmcnt(4)" ::: "memory");
    } else {
      asm volatile("s_waitcnt vmcnt(0)" ::: "memory");
    }
    __builtin_amdgcn_s_barrier();
    if (t + 2 < ntc) STAGE_T(t + 2, sbuf);

    if (k0 <= qmax){
      fx16 st[2];
      __builtin_amdgcn_s_setprio(1);
      #pragma unroll
      for (int s = 0; s < 2; ++s){
        const short* kb = &Ksm[buf][(32 * s + l5) * 64];
        fx16 z;
        #pragma unroll
        for (int i = 0; i < 16; ++i) z[i] = 0.f;
        #pragma unroll
        for (int dblk = 0; dblk < 4; ++dblk){
          s16x8 kf = *(const s16x8*)(kb + ((16 * dblk + 8 * hi) ^ ((l5 & 7) << 3)));
          z = mfma32(kf, qf[dblk], z);
        }
        st[s] = z;
      }
      __builtin_amdgcn_s_setprio(0);
      float p[2][16];
      #pragma unroll
      for (int s = 0; s < 2; ++s)
        #pragma unroll
        for (int m4 = 0; m4 < 4; ++m4){
          fx4 kt4 = *(const fx4*)&Ktm[buf][32 * s + 8 * m4 + 4 * hi];
          #pragma unroll
          for (int tt = 0; tt < 4; ++tt)
            p[s][4 * m4 + tt] = st[s][4 * m4 + tt] + aqt * kt4[tt];
        }
      if (k0 + 63 > q0w){
        #pragma unroll
        for (int s = 0; s < 2; ++s)
          #pragma unroll
          for (int r = 0; r < 16; ++r){
            int kg2 = k0 + 32 * s + (r & 3) + 8 * (r >> 2) + 4 * hi;
            if (kg2 > q) p[s][r] = -3e38f;
          }
      }
      float v16[16];
      #pragma unroll
      for (int i = 0; i < 16; ++i) v16[i] = fmaxf(p[0][i], p[1][i]);
      #pragma unroll
      for (int i = 0; i < 8; ++i) v16[i] = fmaxf(v16[i], v16[i + 8]);
      #pragma unroll
      for (int i = 0; i < 4; ++i) v16[i] = fmaxf(v16[i], v16[i + 4]);
      float pmax = fmaxf(fmaxf(v16[0], v16[1]), fmaxf(v16[2], v16[3]));
      pmax = fmaxf(pmax, __shfl_xor(pmax, 32));
      if (!__all(pmax <= mrun + 8.f)){
        float mnew = fmaxf(mrun, pmax);
        float scl = __builtin_amdgcn_exp2f(mrun - mnew);
        mrun = mnew;
        lrun *= scl;
        #pragma unroll
        for (int i = 0; i < 16; ++i){ acc0[i] *= scl; acc1[i] *= scl; }
      }
      float sm[16];
      #pragma unroll
      for (int i = 0; i < 16; ++i){
        p[0][i] = __builtin_amdgcn_exp2f(p[0][i] - mrun);
        p[1][i] = __builtin_amdgcn_exp2f(p[1][i] - mrun);
        sm[i] = p[0][i] + p[1][i];
      }
      #pragma unroll
      for (int i = 0; i < 8; ++i) sm[i] += sm[i + 8];
      #pragma unroll
      for (int i = 0; i < 4; ++i) sm[i] += sm[i + 4];
      float rsum = (sm[0] + sm[1]) + (sm[2] + sm[3]);
      rsum += __shfl_xor(rsum, 32);
      lrun += rsum;

      #pragma unroll
      for (int h = 0; h < 4; ++h){
        int s = h >> 1, hb = h & 1;
        int w0 = cvtpk(p[s][8 * hb + 0], p[s][8 * hb + 1]);
        int w1 = cvtpk(p[s][8 * hb + 2], p[s][8 * hb + 3]);
        int w2 = cvtpk(p[s][8 * hb + 4], p[s][8 * hb + 5]);
        int w3 = cvtpk(p[s][8 * hb + 6], p[s][8 * hb + 7]);
        int sdA = hi ? w0 : w2;
        int sdB = hi ? w1 : w3;
        int rcA = __shfl_xor(sdA, 32);
        int rcB = __shfl_xor(sdB, 32);
        ix4 fw;
        fw.x = hi ? rcA : w0; fw.y = hi ? rcB : w1;
        fw.z = hi ? w2 : rcA; fw.w = hi ? w3 : rcB;
        s16x8 pf = __builtin_bit_cast(s16x8, fw);
        const short* vb0 = &Vsm[buf][(l5) * 64 + ((16 * h + 8 * hi) ^ ((l5 & 7) << 3))];
        const short* vb1 = vb0 + 32 * 64;
        s16x8 vf0 = *(const s16x8*)vb0;
        s16x8 vf1 = *(const s16x8*)vb1;
        __builtin_amdgcn_s_setprio(1);
        acc0 = mfma32(vf0, pf, acc0);
        acc1 = mfma32(vf1, pf, acc1);
        __builtin_amdgcn_s_setprio(0);
      }
    }
    buf  = (buf == 2)  ? 0 : buf + 1;
    sbuf = (sbuf == 2) ? 0 : sbuf + 1;
  }

  // ---- epilogue: normalized output (acc/l), bf16 ----
  float invl = 1.0f / lrun;
  int qi = 32 * w + l5;
  if (nch == 1){
    // single chunk: write final output directly
    int bb = bh >> 3, hh = bh & 7;
    short* orow = Obf + ((size_t)bb * S_LEN + 128 * g + qi) * DM + hh * DH;
    #pragma unroll
    for (int j = 0; j < 4; ++j){
      ix2 v0, v1;
      v0.x = cvtpk(acc0[4 * j + 0] * invl, acc0[4 * j + 1] * invl);
      v0.y = cvtpk(acc0[4 * j + 2] * invl, acc0[4 * j + 3] * invl);
      v1.x = cvtpk(acc1[4 * j + 0] * invl, acc1[4 * j + 1] * invl);
      v1.y = cvtpk(acc1[4 * j + 2] * invl, acc1[4 * j + 3] * invl);
      *(ix2*)(orow + 8 * j + 4 * hi)      = v0;
      *(ix2*)(orow + 32 + 8 * j + 4 * hi) = v1;
    }
  } else {
    int slot = ((bh << 4) + g) * 4 + c;
    if (hi == 0){
      Mpart[(size_t)slot * 128 + qi] = mrun;
      Lpart[(size_t)slot * 128 + qi] = lrun;
    }
    short* Op = Obn + (size_t)slot * 8192 + (size_t)qi * 64;
    #pragma unroll
    for (int j = 0; j < 4; ++j){
      ix2 v0, v1;
      v0.x = cvtpk(acc0[4 * j + 0] * invl, acc0[4 * j + 1] * invl);
      v0.y = cvtpk(acc0[4 * j + 2] * invl, acc0[4 * j + 3] * invl);
      v1.x = cvtpk(acc1[4 * j + 0] * invl, acc1[4 * j + 1] * invl);
      v1.y = cvtpk(acc1[4 * j + 2] * invl, acc1[4 * j + 3] * invl);
      *(ix2*)(Op + 8 * j + 4 * hi)      = v0;
      *(ix2*)(Op + 32 + 8 * j + 4 * hi) = v1;
    }
  }
}

// ---- K4b: combine bf16 normalized partials -> Obf (only g>=4). 768 blocks ----
__global__ __launch_bounds__(256) void combine_kernel(const float* __restrict__ Mpart,
                                                      const float* __restrict__ Lpart,
                                                      const short* __restrict__ Obn,
                                                      short* __restrict__ Obf){
  int bx = blockIdx.x;
  int bhg = bx % 192;
  int qq = bx / 192;                 // 0..3
  int bh = bhg & 15;
  int g = 4 + (bhg >> 4);            // 4..15
  int t = threadIdx.x;
  int q = qq * 32 + (t >> 3);
  int oct = t & 7;
  int nch = (g >> 2) + 1;
  int gbase = ((bh << 4) + g) * 4;

  float mc[4], lc[4];
  #pragma unroll
  for (int c = 0; c < 4; ++c){
    mc[c] = Mpart[(size_t)(gbase + c) * 128 + q];
    lc[c] = Lpart[(size_t)(gbase + c) * 128 + q];
    if (c >= nch) mc[c] = -3e38f;
  }
  float M = fmaxf(fmaxf(mc[0], mc[1]), fmaxf(mc[2], mc[3]));
  float ww[4]; float D = 0.f;
  #pragma unroll
  for (int c = 0; c < 4; ++c){
    ww[c] = __builtin_amdgcn_exp2f(mc[c] - M) * lc[c];
    if (c >= nch) ww[c] = 0.f;
    D += ww[c];
  }
  float invD = 1.f / D;
  #pragma unroll
  for (int c = 0; c < 4; ++c) ww[c] *= invD;

  const short* ob = Obn + (size_t)gbase * 8192 + (size_t)q * 64 + oct * 8;
  float accf[8] = {0.f,0.f,0.f,0.f,0.f,0.f,0.f,0.f};
  #pragma unroll
  for (int c = 0; c < 4; ++c){
    s16x8 v = *(const s16x8*)(ob + (size_t)c * 8192);
    #pragma unroll
    for (int i = 0; i < 8; ++i) accf[i] += ww[c] * bf2f(v[i]);
  }
  s16x8 pk;
  #pragma unroll
  for (int dd = 0; dd < 8; ++dd) pk[dd] = f2bf(accf[dd]);
  int bb = bh >> 3, hh = bh & 7;
  *(s16x8*)(Obf + ((size_t)bb * S_LEN + 128 * g + q) * DM + hh * DH + oct * 8) = pk;
}

// ---- K5: O-projection GEMM, 64x64 tiles, single-barrier loop ----
__global__ __launch_bounds__(256, 4) void gemm_o_kernel(const short* __restrict__ A,
                                                        const short* __restrict__ Bt,
                                                        float* __restrict__ C){
  __shared__ __attribute__((aligned(16))) short Asm[2][64 * 64];
  __shared__ __attribute__((aligned(16))) short Bsm[2][64 * 64];
  const int K = DM;
  int n0 = blockIdx.y * 64, m0 = blockIdx.x * 64;
  int t = threadIdx.x;
  int w = t >> 6, lane = t & 63;
  int wm = w >> 1, wn = w & 1;
  int lg = lane >> 4, lr = lane & 15;

  int aoff[2]; const short* asrcp[2];
  int boff[2]; const short* bsrcp[2];
  #pragma unroll
  for (int j = 0; j < 2; ++j){
    int ch = t + 256 * j;
    int r = ch >> 3, c = ch & 7;
    aoff[j] = ch * 8;
    asrcp[j] = A + (size_t)(m0 + r) * K + 8 * (c ^ (r & 7));
    boff[j] = ch * 8;
    bsrcp[j] = Bt + (size_t)(n0 + r) * K + 8 * (c ^ (r & 7));
  }

  {
    short* ab = &Asm[0][0]; short* bb = &Bsm[0][0];
    #pragma unroll
    for (int j = 0; j < 2; ++j){ GLL16(asrcp[j], ab + aoff[j]); GLL16(bsrcp[j], bb + boff[j]); }
  }

  fx4 acc[2][2] = {};
  for (int ks = 0; ks < 8; ++ks){
    asm volatile("s_waitcnt vmcnt(0)" ::: "memory");
    __builtin_amdgcn_s_barrier();
    if (ks < 7){
      int nb = (ks + 1) & 1;
      short* ab = &Asm[nb][0]; short* bb = &Bsm[nb][0];
      int kk = (ks + 1) * 64;
      #pragma unroll
      for (int j = 0; j < 2; ++j){ GLL16(asrcp[j] + kk, ab + aoff[j]); GLL16(bsrcp[j] + kk, bb + boff[j]); }
    }
    int buf = ks & 1;
    s16x8 af[2][2], bf[2][2];
    #pragma unroll
    for (int mi = 0; mi < 2; ++mi){
      int row = wm * 32 + mi * 16 + lr;
      #pragma unroll
      for (int s = 0; s < 2; ++s)
        af[mi][s] = *(const s16x8*)&Asm[buf][row * 64 + ((4 * s + lg) ^ (row & 7)) * 8];
    }
    #pragma unroll
    for (int ni = 0; ni < 2; ++ni){
      int row = wn * 32 + ni * 16 + lr;
      #pragma unroll
      for (int s = 0; s < 2; ++s)
        bf[ni][s] = *(const s16x8*)&Bsm[buf][row * 64 + ((4 * s + lg) ^ (row & 7)) * 8];
    }
    __builtin_amdgcn_s_setprio(1);
    #pragma unroll
    for (int s = 0; s < 2; ++s)
      #pragma unroll
      for (int mi = 0; mi < 2; ++mi)
        #pragma unroll
        for (int ni = 0; ni < 2; ++ni)
          acc[mi][ni] = mfma16(af[mi][s], bf[ni][s], acc[mi][ni]);
    __builtin_amdgcn_s_setprio(0);
  }

  #pragma unroll
  for (int mi = 0; mi < 2; ++mi)
    #pragma unroll
    for (int ni = 0; ni < 2; ++ni)
      #pragma unroll
      for (int r = 0; r < 4; ++r){
        int row = m0 + wm * 32 + mi * 16 + 4 * lg + r;
        int col = n0 + wn * 32 + ni * 16 + lr;
        C[(size_t)row * DM + col] = acc[mi][ni][r];
      }
}

extern "C" void kernel_launch(void* const* d_in, const int* in_sizes, int n_in,
                              void* d_out, int out_size, void* d_ws, size_t ws_size,
                              hipStream_t stream) {
  const float* x     = (const float*)d_in[0];
  const float* Wq    = (const float*)d_in[1];
  const float* Wk    = (const float*)d_in[2];
  const float* Wv    = (const float*)d_in[3];
  const float* Wo    = (const float*)d_in[4];
  const float* labsK = (const float*)d_in[5];

  char* w = (char*)d_ws;
  short* Wt    = (short*)(w);                                  // 2 MB
  short* xeu   = (short*)(w + (2ull  << 20));                  // 4 MB
  short* Qs    = (short*)(w + (30ull << 20));                  // 4 MB
  short* Ks    = (short*)(w + (34ull << 20));                  // 4 MB
  short* Vt    = (short*)(w + (38ull << 20));                  // 4 MB
  float* Qt    = (float*)(w + (42ull << 20));                  // 128 KB
  float* Kt    = (float*)(w + (42ull << 20) + (128ull << 10)); // 128 KB
  short* Obf   = (short*)(w + (42ull << 20) + (256ull << 10)); // 4 MB
  short* Obn   = (short*)(w + (48ull << 20));                  // 16 MB (bf16 partials)
  float* Mpart = (float*)(w + (80ull << 20));                  // 512 KB
  float* Lpart = (float*)(w + (81ull << 20));                  // 512 KB

  prep_kernel<<<dim3(1280), 256, 0, stream>>>(Wq, Wk, Wv, Wo, Wt, x, xeu);

  gemm_fused_kernel<<<dim3(32, 4, 3), 256, 0, stream>>>(
      xeu, Wt, labsK, Qt, Qs, Kt, Ks, Vt);

  attn_kernel<<<dim3(640), 256, 0, stream>>>(
      Qs, Qt, Ks, Kt, Vt, Mpart, Lpart, Obn, Obf);

  combine_kernel<<<dim3(768), 256, 0, stream>>>(Mpart, Lpart, Obn, Obf);

  gemm_o_kernel<<<dim3(64, 8), 256, 0, stream>>>(Obf, Wt + 3 * DM * DM, (float*)d_out);
}